// Round 3
// baseline (786.418 us; speedup 1.0000x reference)
//
#include <hip/hip_runtime.h>

// MultiHeadAttention fwd: B=4, S=2048, DM=512, H=8, d=64.
// d_out = [Y | att_ws] in the HARNESS dtype, which we detect on-device:
// detect_k inspects bit pattern of Q (fp32 mantissa bits vs bf16-pair
// exponent bits) and writes a flag; all raw-input loads and final stores
// branch on it. Internal pipeline is bf16 MFMA throughout.
// Scratch: ws = flag + mask/bias bf16 + kh + vtb + ctx + wot  (~25.7 MB).
// qh lives at d_out[0] (Y region, dead before final proj). wqt/wkt/wvt live
// at d_out byte offset 4*YELEMS (att region in both dtype modes, dead
// before attn overwrites att).

typedef __bf16 bf16;
typedef __bf16 bf16x8 __attribute__((ext_vector_type(8)));
typedef float f32x4 __attribute__((ext_vector_type(4)));

constexpr int BATCH = 4;
constexpr int SEQ = 2048;
constexpr int DMODEL = 512;
constexpr int NHEAD = 8;
constexpr int HDIM = 64;
constexpr int MTOT = BATCH * SEQ;                  // 8192
constexpr long YELEMS = (long)MTOT * DMODEL;       // 4194304
constexpr long WELEMS = (long)DMODEL * DMODEL;     // 262144

__device__ __forceinline__ f32x4 mfma_bf16(bf16x8 a, bf16x8 b, f32x4 c) {
  return __builtin_amdgcn_mfma_f32_16x16x32_bf16(a, b, c, 0, 0, 0);
}

// ---------------------------------------------------------------- detector
// fp32 data: bits 14..7 are mantissa bits -> uniform (~25% in [0x60,0x9f]).
// bf16-pair data: bits 14..7 are the low element's exponent -> ~100% there
// for N(0,1)-scale values. 64 samples, threshold 48.
__global__ void detect_k(const unsigned int* q, int* flag) {
  unsigned u = q[threadIdx.x];
  int e = (u >> 7) & 0xff;
  unsigned long long m = __ballot(e >= 0x60 && e <= 0x9f);
  if (threadIdx.x == 0) flag[0] = (__popcll(m) >= 48) ? 1 : 0;  // 1 = bf16
}

// ------------------------------------------------------------- small convert
__global__ void cvt_k(const void* src, bf16* dst, int n, const int* flag) {
  int i = blockIdx.x * 256 + threadIdx.x;
  if (i >= n) return;
  dst[i] = (*flag) ? ((const bf16*)src)[i] : (bf16)((const float*)src)[i];
}

// ---------------------------------------------------------------- W transpose
__global__ __launch_bounds__(256) void transpose_w_k(const void* __restrict__ w,
                                                     bf16* __restrict__ wt,
                                                     const int* flag) {
  __shared__ bf16 t[32][33];
  const int f = *flag;
  const int bx = blockIdx.x * 32, by = blockIdx.y * 32;
  const int tx = threadIdx.x & 31, ty = threadIdx.x >> 5;
  for (int i = ty; i < 32; i += 8) {
    const long idx = (long)(by + i) * DMODEL + bx + tx;
    t[i][tx] = f ? ((const bf16*)w)[idx] : (bf16)((const float*)w)[idx];
  }
  __syncthreads();
  for (int i = ty; i < 32; i += 8)
    wt[(long)(bx + i) * DMODEL + by + tx] = t[tx][i];
}

__device__ __forceinline__ void ld8_f32(bf16* dst, const float* p) {
  float4 a = *(const float4*)p;
  float4 b = *(const float4*)(p + 4);
  bf16x8 v;
  v[0] = (bf16)a.x; v[1] = (bf16)a.y; v[2] = (bf16)a.z; v[3] = (bf16)a.w;
  v[4] = (bf16)b.x; v[5] = (bf16)b.y; v[6] = (bf16)b.z; v[7] = (bf16)b.w;
  *(bf16x8*)dst = v;
}

// ------------------------------------------------------- 64x64-tile bf16 GEMM
// out = X[8192,512] @ Wt^T + bias. Wt [n][k] bf16. bias bf16.
// mode 0: out[row][col] in HARNESS dtype (final Y)
// mode 1: out[b*H+h][s][d] bf16 ; mode 2: out[b*H+h][d][s] bf16
// x_raw: X is a raw harness input (dtype per flag); else X is bf16.
__global__ __launch_bounds__(256) void proj_gemm(
    const void* __restrict__ X, const bf16* __restrict__ Wt,
    const bf16* __restrict__ bias, void* __restrict__ out, int mode, int x_raw,
    const int* flag) {
  __shared__ __attribute__((aligned(16))) bf16 As[64][72];
  __shared__ __attribute__((aligned(16))) bf16 Bs[64][72];
  const int f = *flag;
  const int xf = x_raw ? f : 1;  // 1 => X is bf16
  const int r0 = blockIdx.x * 64;
  const int c0 = blockIdx.y * 64;
  const int tid = threadIdx.x;
  const int wave = tid >> 6, lane = tid & 63;
  const int quad = lane >> 4, l16 = lane & 15;
  const int srow = tid >> 3, scb = (tid & 7) * 8;

  f32x4 acc[4] = {};
  for (int k0 = 0; k0 < DMODEL; k0 += 64) {
    __syncthreads();
    const long xi0 = (long)(r0 + srow) * DMODEL + k0 + scb;
    const long xi1 = (long)(r0 + srow + 32) * DMODEL + k0 + scb;
    if (xf) {
      *(uint4*)&As[srow][scb] = *(const uint4*)((const bf16*)X + xi0);
      *(uint4*)&As[srow + 32][scb] = *(const uint4*)((const bf16*)X + xi1);
    } else {
      ld8_f32(&As[srow][scb], (const float*)X + xi0);
      ld8_f32(&As[srow + 32][scb], (const float*)X + xi1);
    }
    *(uint4*)&Bs[srow][scb] =
        *(const uint4*)(Wt + (long)(c0 + srow) * DMODEL + k0 + scb);
    *(uint4*)&Bs[srow + 32][scb] =
        *(const uint4*)(Wt + (long)(c0 + srow + 32) * DMODEL + k0 + scb);
    __syncthreads();
    const int m = wave * 16 + l16;
#pragma unroll
    for (int kk = 0; kk < 64; kk += 32) {
      bf16x8 a = *(const bf16x8*)&As[m][kk + quad * 8];
#pragma unroll
      for (int n = 0; n < 4; n++) {
        bf16x8 bb8 = *(const bf16x8*)&Bs[n * 16 + l16][kk + quad * 8];
        acc[n] = mfma_bf16(a, bb8, acc[n]);
      }
    }
  }

  __syncthreads();
  const bool f32out = (mode == 0) && !f;
#pragma unroll
  for (int n = 0; n < 4; n++) {
    const float bvv = (float)bias[c0 + n * 16 + l16];
#pragma unroll
    for (int r = 0; r < 4; r++) {
      const float v = acc[n][r] + bvv;
      const int ml = wave * 16 + quad * 4 + r;  // C/D: row = quad*4 + reg
      const int nl = n * 16 + l16;
      if (f32out) {
        ((float*)out)[(long)(r0 + ml) * DMODEL + c0 + nl] = v;
      } else if (mode == 2) {
        As[nl][ml] = (bf16)v;  // transposed stage [col][row]
      } else {
        As[ml][nl] = (bf16)v;  // row-major stage [row][col]
      }
    }
  }
  if (f32out) return;
  __syncthreads();

  const int rb = r0 >> 11;        // batch
  const int s0 = r0 & (SEQ - 1);  // seq base
  const int hh = c0 >> 6;         // head
  bf16* ob = (bf16*)out;
#pragma unroll
  for (int i = 0; i < 2; i++) {
    const int mrow = srow + i * 32;
    long idx;
    if (mode == 0) {
      idx = (long)(r0 + mrow) * DMODEL + c0 + scb;
    } else if (mode == 1) {
      idx = (((long)(rb * NHEAD + hh) * SEQ) + s0 + mrow) * HDIM + scb;
    } else {  // mode 2: [bh][d][s]
      idx = (((long)(rb * NHEAD + hh) * HDIM) + mrow) * SEQ + s0 + scb;
    }
    *(uint4*)(ob + idx) = *(const uint4*)&As[mrow][scb];
  }
}

// ------------------------------------------------------- two-pass attention
__global__ __launch_bounds__(256) void attn_k(
    const bf16* __restrict__ qh, const bf16* __restrict__ kh,
    const bf16* __restrict__ vt, const bf16* __restrict__ mask_c,
    bf16* __restrict__ attB, float* __restrict__ attF, bf16* __restrict__ ctx,
    const int* flag) {
  __shared__ __attribute__((aligned(16))) bf16 qs[64][72];
  __shared__ __attribute__((aligned(16))) bf16 ks[64][72];
  __shared__ __attribute__((aligned(16))) bf16 vs[64][72];  // [d][key]
  __shared__ __attribute__((aligned(16))) bf16 ps[64][72];  // [q][key]
  __shared__ float mk[64];

  const int f = *flag;
  const int bh = blockIdx.y;
  const int bb = bh >> 3, hh = bh & 7;
  const int q0 = blockIdx.x * 64;
  const int tid = threadIdx.x;
  const int wave = tid >> 6, lane = tid & 63;
  const int quad = lane >> 4, l16 = lane & 15;
  const int srow = tid >> 3, scb = (tid & 7) * 8;
  const float scale = 0.125f;

  const bf16* qp = qh + ((long)bh * SEQ + q0) * HDIM;
  const bf16* kp = kh + (long)bh * SEQ * HDIM;
  const bf16* vp = vt + (long)bh * HDIM * SEQ;
  const bf16* mp = mask_c + (long)bb * SEQ;

  *(uint4*)&qs[srow][scb] = *(const uint4*)(qp + (long)srow * HDIM + scb);
  *(uint4*)&qs[srow + 32][scb] =
      *(const uint4*)(qp + (long)(srow + 32) * HDIM + scb);

  float m_ln[4], l_ln[4];
#pragma unroll
  for (int r = 0; r < 4; r++) { m_ln[r] = -3e38f; l_ln[r] = 0.f; }
  const int mrow = wave * 16 + l16;

  // ---- pass 1: per-lane online (m, l)
  for (int t = 0; t < SEQ / 64; t++) {
    __syncthreads();
    const bf16* kt = kp + (long)t * 64 * HDIM;
    *(uint4*)&ks[srow][scb] = *(const uint4*)(kt + (long)srow * HDIM + scb);
    *(uint4*)&ks[srow + 32][scb] =
        *(const uint4*)(kt + (long)(srow + 32) * HDIM + scb);
    if (tid < 64) mk[tid] = -1e9f * (float)mp[t * 64 + tid];
    __syncthreads();
    f32x4 sc[4] = {};
#pragma unroll
    for (int kk = 0; kk < 64; kk += 32) {
      bf16x8 a = *(const bf16x8*)&qs[mrow][kk + quad * 8];
#pragma unroll
      for (int n = 0; n < 4; n++) {
        bf16x8 bb8 = *(const bf16x8*)&ks[n * 16 + l16][kk + quad * 8];
        sc[n] = mfma_bf16(a, bb8, sc[n]);
      }
    }
    float mv[4];
#pragma unroll
    for (int n = 0; n < 4; n++) mv[n] = mk[n * 16 + l16];
#pragma unroll
    for (int r = 0; r < 4; r++) {
      const float v0 = sc[0][r] * scale + mv[0];
      const float v1 = sc[1][r] * scale + mv[1];
      const float v2 = sc[2][r] * scale + mv[2];
      const float v3 = sc[3][r] * scale + mv[3];
      const float mx = fmaxf(fmaxf(v0, v1), fmaxf(v2, v3));
      const float mnew = fmaxf(m_ln[r], mx);
      l_ln[r] = l_ln[r] * __expf(m_ln[r] - mnew) + __expf(v0 - mnew) +
                __expf(v1 - mnew) + __expf(v2 - mnew) + __expf(v3 - mnew);
      m_ln[r] = mnew;
    }
  }

  // ---- merge across the 16 lanes of each C-row
  float m_i[4], rcl[4];
#pragma unroll
  for (int r = 0; r < 4; r++) {
    float mr = m_ln[r];
#pragma unroll
    for (int o = 1; o < 16; o <<= 1) mr = fmaxf(mr, __shfl_xor(mr, o, 64));
    float lr = l_ln[r] * __expf(m_ln[r] - mr);
#pragma unroll
    for (int o = 1; o < 16; o <<= 1) lr += __shfl_xor(lr, o, 64);
    m_i[r] = mr;
    rcl[r] = 1.f / lr;
  }

  // ---- pass 2
  f32x4 oacc[4] = {};
  const long abase = ((long)bh * SEQ + q0) * SEQ;

  for (int t = 0; t < SEQ / 64; t++) {
    __syncthreads();
    const bf16* kt = kp + (long)t * 64 * HDIM;
    *(uint4*)&ks[srow][scb] = *(const uint4*)(kt + (long)srow * HDIM + scb);
    *(uint4*)&ks[srow + 32][scb] =
        *(const uint4*)(kt + (long)(srow + 32) * HDIM + scb);
    *(uint4*)&vs[srow][scb] =
        *(const uint4*)(vp + (long)srow * SEQ + t * 64 + scb);
    *(uint4*)&vs[srow + 32][scb] =
        *(const uint4*)(vp + (long)(srow + 32) * SEQ + t * 64 + scb);
    if (tid < 64) mk[tid] = -1e9f * (float)mp[t * 64 + tid];
    __syncthreads();
    f32x4 sc[4] = {};
#pragma unroll
    for (int kk = 0; kk < 64; kk += 32) {
      bf16x8 a = *(const bf16x8*)&qs[mrow][kk + quad * 8];
#pragma unroll
      for (int n = 0; n < 4; n++) {
        bf16x8 bb8 = *(const bf16x8*)&ks[n * 16 + l16][kk + quad * 8];
        sc[n] = mfma_bf16(a, bb8, sc[n]);
      }
    }
    float mv[4];
#pragma unroll
    for (int n = 0; n < 4; n++) mv[n] = mk[n * 16 + l16];
#pragma unroll
    for (int r = 0; r < 4; r++) {
      const int prow = wave * 16 + quad * 4 + r;
#pragma unroll
      for (int n = 0; n < 4; n++) {
        const float p = __expf(sc[n][r] * scale + mv[n] - m_i[r]) * rcl[r];
        ps[prow][n * 16 + l16] = (bf16)p;
        if (!f) attF[abase + (long)prow * SEQ + t * 64 + n * 16 + l16] = p;
      }
    }
    __syncthreads();
#pragma unroll
    for (int kk = 0; kk < 64; kk += 32) {
      bf16x8 a = *(const bf16x8*)&ps[wave * 16 + l16][kk + quad * 8];
#pragma unroll
      for (int n = 0; n < 4; n++) {
        bf16x8 bb8 = *(const bf16x8*)&vs[n * 16 + l16][kk + quad * 8];
        oacc[n] = mfma_bf16(a, bb8, oacc[n]);
      }
    }
    if (f) {
#pragma unroll
      for (int i = 0; i < 2; i++) {
        const int ci = lane + i * 64;
        const int rr = ci >> 3, cc = (ci & 7) * 8;
        *(uint4*)(attB + abase + (long)(wave * 16 + rr) * SEQ + t * 64 + cc) =
            *(const uint4*)&ps[wave * 16 + rr][cc];
      }
    }
  }

  // ---- ctx [B][S][DM] bf16
#pragma unroll
  for (int n = 0; n < 4; n++) {
#pragma unroll
    for (int r = 0; r < 4; r++) {
      const int s = q0 + wave * 16 + quad * 4 + r;
      const int d = n * 16 + l16;
      ctx[((long)bb * SEQ + s) * DMODEL + hh * HDIM + d] = (bf16)oacc[n][r];
    }
  }
}

// ----------------------------------------------------------------- launcher
extern "C" void kernel_launch(void* const* d_in, const int* in_sizes, int n_in,
                              void* d_out, int out_size, void* d_ws,
                              size_t ws_size, hipStream_t stream) {
  const void* Q = d_in[0];
  const void* K = d_in[1];
  const void* V = d_in[2];
  const void* mask = d_in[3];
  const void* Wq = d_in[4];
  const void* bq = d_in[5];
  const void* Wk = d_in[6];
  const void* bk = d_in[7];
  const void* Wv = d_in[8];
  const void* bv = d_in[9];
  const void* Wo = d_in[10];
  const void* bo = d_in[11];

  char* ob = (char*)d_out;
  bf16* attB = (bf16*)(ob + 2 * YELEMS);  // bf16-mode att base
  float* attF = (float*)(ob + 4 * YELEMS);  // fp32-mode att base
  bf16* qh = (bf16*)ob;  // Y region scratch, dead before final proj

  // staging in att region (safe both modes; dead before attn writes att)
  bf16* stg = (bf16*)(ob + 4 * YELEMS);
  bf16* wqt = stg;
  bf16* wkt = wqt + WELEMS;
  bf16* wvt = wkt + WELEMS;

  // ws: flag + converted mask/biases + persistent bf16 buffers (~25.7 MB)
  char* wb = (char*)d_ws;
  int* flag = (int*)wb;
  bf16* mask_c = (bf16*)(wb + 16);              // 8192 elems
  bf16* bq_c = (bf16*)(wb + 16 + 16384);        // 512 each
  bf16* bk_c = bq_c + 512;
  bf16* bv_c = bk_c + 512;
  bf16* bo_c = bv_c + 512;
  bf16* kh = (bf16*)(wb + 20496);
  bf16* vtb = kh + YELEMS;
  bf16* ctx = vtb + YELEMS;
  bf16* wot = ctx + YELEMS;

  dim3 tb(256);
  detect_k<<<1, 64, 0, stream>>>((const unsigned int*)Q, flag);

  cvt_k<<<32, 256, 0, stream>>>(mask, mask_c, BATCH * SEQ, flag);
  cvt_k<<<2, 256, 0, stream>>>(bq, bq_c, DMODEL, flag);
  cvt_k<<<2, 256, 0, stream>>>(bk, bk_c, DMODEL, flag);
  cvt_k<<<2, 256, 0, stream>>>(bv, bv_c, DMODEL, flag);
  cvt_k<<<2, 256, 0, stream>>>(bo, bo_c, DMODEL, flag);

  dim3 gw(DMODEL / 32, DMODEL / 32);
  transpose_w_k<<<gw, tb, 0, stream>>>(Wq, wqt, flag);
  transpose_w_k<<<gw, tb, 0, stream>>>(Wk, wkt, flag);
  transpose_w_k<<<gw, tb, 0, stream>>>(Wv, wvt, flag);
  transpose_w_k<<<gw, tb, 0, stream>>>(Wo, wot, flag);

  dim3 gp(MTOT / 64, DMODEL / 64);
  proj_gemm<<<gp, tb, 0, stream>>>(Q, wqt, bq_c, qh, 1, 1, flag);
  proj_gemm<<<gp, tb, 0, stream>>>(K, wkt, bk_c, kh, 1, 1, flag);
  proj_gemm<<<gp, tb, 0, stream>>>(V, wvt, bv_c, vtb, 2, 1, flag);

  attn_k<<<dim3(SEQ / 64, BATCH * NHEAD), tb, 0, stream>>>(
      qh, kh, vtb, mask_c, attB, attF, ctx, flag);

  proj_gemm<<<gp, tb, 0, stream>>>(ctx, wot, bo_c, d_out, 0, 0, flag);
}